// Round 1
// 781.563 us; speedup vs baseline: 1.1393x; 1.1393x over previous
//
#include <hip/hip_runtime.h>
#include <math.h>
#include <stdint.h>

// VQActivation residual VQ, depth=4. x:(32,256,56,56) f32, cb:(1024,256) f32.
//
// Round-2 PASSED semantics preserved exactly: decisions = np f32 sgemm =
// sequential fmaf chain over k ascending, single f32 accumulator; u = that
// bitwise max; resid -= fl(cb*u) with separate roundings; out re-summed in
// np's exact f32 add order.
//
// Round-3 (this round): attack VALU work + per-iteration L2 latency:
//   * Phase A conversion via v_cvt_pk_bf16_f32 (64 insts vs ~700 bit-twiddle)
//   * candidate-phase inserts use plain float compares (no np tie-break --
//     the exact re-rank in Phase B fixes ordering; candidates only need to
//     CONTAIN the winner). Exact BET kept in the final exact reduce only.
//   * B-fragment register ping-pong: load tile i+1 while MFMA'ing tile i.
//     Per-lane top-2 codes packed into one u32 (c1<<16|c2) to stay within
//     the 3-waves/SIMD register budget.

#define KDIM 256
#define KSZ  1024
#define TM   32
#define HWSZ 3136
#define NBLK (HWSZ/TM)   // 98 row-blocks per image
#define RSTR 260         // resid row stride (f32): 16B-aligned, bank-skewed
#define MAXD 16

using f32x4  = __attribute__((ext_vector_type(4))) float;
using bf16x8 = __attribute__((ext_vector_type(8))) short;

static __device__ __forceinline__ unsigned short f2bf(float f) {
    unsigned u = __float_as_uint(f);
    u += 0x7fffu + ((u >> 16) & 1u);
    return (unsigned short)(u >> 16);
}

// 8 f32 -> 8 bf16 via 4x v_cvt_pk_bf16_f32 (lo = first operand, RNE).
static __device__ __forceinline__ bf16x8 pk8(const float4 a, const float4 b) {
    union { unsigned u[4]; bf16x8 v; } r;
    asm("v_cvt_pk_bf16_f32 %0, %1, %2" : "=v"(r.u[0]) : "v"(a.x), "v"(a.y));
    asm("v_cvt_pk_bf16_f32 %0, %1, %2" : "=v"(r.u[1]) : "v"(a.z), "v"(a.w));
    asm("v_cvt_pk_bf16_f32 %0, %1, %2" : "=v"(r.u[2]) : "v"(b.x), "v"(b.y));
    asm("v_cvt_pk_bf16_f32 %0, %1, %2" : "=v"(r.u[3]) : "v"(b.z), "v"(b.w));
    return r.v;
}

// Candidate-phase inserts: plain value compare. Ties resolved arbitrarily --
// harmless, since the winner is re-ranked with exact np arithmetic later.
static __device__ __forceinline__ void ins3(float vv, int cx,
    float& w1, int& d1, float& w2, int& d2, float& w3, int& d3) {
    const bool b1 = vv > w1, b2 = vv > w2, b3 = vv > w3;
    w3 = b2 ? w2 : (b3 ? vv : w3);  d3 = b2 ? d2 : (b3 ? cx : d3);
    w2 = b1 ? w1 : (b2 ? vv : w2);  d2 = b1 ? d1 : (b2 ? cx : d2);
    w1 = b1 ? vv : w1;              d1 = b1 ? cx : d1;
}

static __device__ __forceinline__ void ins4(float vv, int cx,
    float& w1, int& d1, float& w2, int& d2,
    float& w3, int& d3, float& w4, int& d4) {
    const bool b1 = vv > w1, b2 = vv > w2;
    const bool b3 = vv > w3, b4 = vv > w4;
    w4 = b3 ? w3 : (b4 ? vv : w4);  d4 = b3 ? d3 : (b4 ? cx : d4);
    w3 = b2 ? w2 : (b3 ? vv : w3);  d3 = b2 ? d2 : (b3 ? cx : d3);
    w2 = b1 ? w1 : (b2 ? vv : w2);  d2 = b1 ? d1 : (b2 ? cx : d2);
    w1 = b1 ? vv : w1;              d1 = b1 ? cx : d1;
}

// Per-slot top-2 update with codes packed (c1<<16 | c2); codes < 1024.
static __device__ __forceinline__ void upd2(float vv, unsigned cc,
    float& v1, float& v2, unsigned& c12) {
    const bool g1 = vv > v1, g2 = vv > v2;
    const unsigned t1 = (cc << 16) | (c12 >> 16);        // c1'=cc, c2'=old c1
    const unsigned t2 = (c12 & 0xFFFF0000u) | cc;        // c2'=cc
    v2  = g1 ? v1 : (g2 ? vv : v2);
    v1  = g1 ? vv : v1;
    c12 = g1 ? t1 : (g2 ? t2 : c12);
}

// ---- pack cb f32 [1024][256] into MFMA-B-fragment-native bf16 (512 KB) ----
// frag f = (tg*8 + kt)*64 + lane ; lane = n + 16*q holds
// cb[tg*16+n][kt*32 + q*8 + 0..7] as 8 bf16 (16 B).
__global__ __launch_bounds__(256)
void make_cb_frag(const float* __restrict__ cb, bf16x8* __restrict__ cbf)
{
    const int f    = blockIdx.x * 256 + threadIdx.x;   // 0..32767
    const int lane = f & 63, kt = (f >> 6) & 7, tg = f >> 9;
    const int n = lane & 15, q = lane >> 4;
    const float* src = cb + ((size_t)(tg * 16 + n)) * KDIM + kt * 32 + q * 8;
    const float4 a = ((const float4*)src)[0];
    const float4 b = ((const float4*)src)[1];
    bf16x8 s;
    s[0] = (short)f2bf(a.x); s[1] = (short)f2bf(a.y);
    s[2] = (short)f2bf(a.z); s[3] = (short)f2bf(a.w);
    s[4] = (short)f2bf(b.x); s[5] = (short)f2bf(b.y);
    s[6] = (short)f2bf(b.z); s[7] = (short)f2bf(b.w);
    cbf[f] = s;
}

__global__ __launch_bounds__(256, 3)
void vq_kernel(const float* __restrict__ x,
               const float* __restrict__ cb,
               const bf16x8* __restrict__ cbf,
               const int*   __restrict__ depth_p,
               float*       __restrict__ out)
{
    __shared__ float resid[TM][RSTR];        // 33,280 B, np-bitwise residual
    __shared__ float entV[TM][4][4][3];      // [row][quarter][group][3]
    __shared__ int   entC[TM][4][4][3];      // 12,288 B total
    __shared__ float u_all[MAXD][TM];        // winning u per depth (bitwise np)
    __shared__ int   c_all[MAXD][TM];        // winning code per depth

    const int tid  = threadIdx.x;
    const int bidx = blockIdx.x;
    const int b    = bidx / NBLK;
    const int hw0  = (bidx % NBLK) * TM;
    const int depth = depth_p[0];
    const int lane = tid & 63, w = tid >> 6;     // wave w = code quarter
    const int n = lane & 15, q = lane >> 4;
    const int wbase = w * 256;

    // ---- stage x -> resid (coalesced along hw) ----
    {
        const int r = tid & 31, ks = tid >> 5;
        const float* xp = x + ((size_t)b * KDIM + ks * 32) * HWSZ + hw0 + r;
        for (int m = 0; m < 32; ++m)
            resid[r][ks * 32 + m] = xp[(size_t)m * HWSZ];
    }
    __syncthreads();

    const bf16x8* bp0 = cbf + (size_t)w * 8192 + lane;

    for (int d = 0; d < depth; ++d) {
        // ---- issue first B-tile loads early (latency hides under cvt) ----
        bf16x8 bA[8], bB[8];
#pragma unroll
        for (int kt = 0; kt < 8; ++kt) bA[kt] = bp0[kt * 64];

        // ---- A-fragments (bf16) via packed converts: rows 0..15, 16..31 ----
        bf16x8 fa0[8], fa1[8];
#pragma unroll
        for (int kt = 0; kt < 8; ++kt) {
            const float* s0 = &resid[n][kt * 32 + q * 8];
            const float* s1 = &resid[16 + n][kt * 32 + q * 8];
            fa0[kt] = pk8(((const float4*)s0)[0], ((const float4*)s0)[1]);
            fa1[kt] = pk8(((const float4*)s1)[0], ((const float4*)s1)[1]);
        }

        // ---- MFMA GEMM over this wave's 256 codes + per-lane top-2 ----
        float v1[8], v2[8]; unsigned c12[8];
#pragma unroll
        for (int e = 0; e < 8; ++e) { v1[e] = -INFINITY; v2[e] = -INFINITY; c12[e] = 0xFFFFFFFFu; }

#define MFMA_SELECT(BB, I)                                                        \
        {                                                                         \
            f32x4 A0 = {0.f, 0.f, 0.f, 0.f};                                      \
            f32x4 A1 = {0.f, 0.f, 0.f, 0.f};                                      \
            _Pragma("unroll")                                                     \
            for (int kt = 0; kt < 8; ++kt) {                                      \
                A0 = __builtin_amdgcn_mfma_f32_16x16x32_bf16(fa0[kt], BB[kt], A0, 0, 0, 0); \
                A1 = __builtin_amdgcn_mfma_f32_16x16x32_bf16(fa1[kt], BB[kt], A1, 0, 0, 0); \
            }                                                                     \
            const unsigned cc = (unsigned)(wbase + (I) * 16 + n);                 \
            _Pragma("unroll")                                                     \
            for (int e = 0; e < 4; ++e) {                                         \
                upd2(A0[e], cc, v1[e],   v2[e],   c12[e]);                        \
                upd2(A1[e], cc, v1[4+e], v2[4+e], c12[4+e]);                      \
            }                                                                     \
        }

        for (int ii = 0; ii < 8; ++ii) {
            const bf16x8* bpB = bp0 + (size_t)(2 * ii + 1) * 512;
#pragma unroll
            for (int kt = 0; kt < 8; ++kt) bB[kt] = bpB[kt * 64];
            MFMA_SELECT(bA, 2 * ii);
            if (ii < 7) {
                const bf16x8* bpA = bp0 + (size_t)(2 * ii + 2) * 512;
#pragma unroll
                for (int kt = 0; kt < 8; ++kt) bA[kt] = bpA[kt * 64];
            }
            MFMA_SELECT(bB, 2 * ii + 1);
        }
#undef MFMA_SELECT

        // ---- extend to top-3, merge across lane pairs (xor 1, xor 2) ----
        float w1[8], w2[8], w3[8]; int d1[8], d2[8], d3[8];
#pragma unroll
        for (int e = 0; e < 8; ++e) {
            w1[e] = v1[e]; d1[e] = (int)(c12[e] >> 16);
            w2[e] = v2[e]; d2[e] = (int)(c12[e] & 0xFFFFu);
            w3[e] = -INFINITY; d3[e] = 0xFFFF;
        }
#pragma unroll
        for (int m = 1; m <= 2; m <<= 1) {
#pragma unroll
            for (int e = 0; e < 8; ++e) {
                const float o1 = __shfl_xor(w1[e], m, 64); const int p1 = __shfl_xor(d1[e], m, 64);
                const float o2 = __shfl_xor(w2[e], m, 64); const int p2 = __shfl_xor(d2[e], m, 64);
                const float o3 = __shfl_xor(w3[e], m, 64); const int p3 = __shfl_xor(d3[e], m, 64);
                ins3(o1, p1, w1[e], d1[e], w2[e], d2[e], w3[e], d3[e]);
                ins3(o2, p2, w1[e], d1[e], w2[e], d2[e], w3[e], d3[e]);
                ins3(o3, p3, w1[e], d1[e], w2[e], d2[e], w3[e], d3[e]);
            }
        }
        if ((n & 3) == 0) {
            const int g = n >> 2;
#pragma unroll
            for (int e = 0; e < 8; ++e) {
                const int row = (e < 4) ? (q * 4 + e) : (16 + q * 4 + (e - 4));
                entV[row][w][g][0] = w1[e]; entC[row][w][g][0] = d1[e];
                entV[row][w][g][1] = w2[e]; entC[row][w][g][1] = d2[e];
                entV[row][w][g][2] = w3[e]; entC[row][w][g][2] = d3[e];
            }
        }
        __syncthreads();

        // ---- Phase B: per-row top-4 candidates + EXACT np-bitwise re-rank ----
        if (tid < 128) {
            const int row = tid >> 2, j = tid & 3;
            float q1 = -INFINITY, q2 = -INFINITY, q3 = -INFINITY, q4 = -INFINITY;
            int   e1 = 0x7fffffff, e2 = 0x7fffffff, e3 = 0x7fffffff, e4 = 0x7fffffff;
#pragma unroll
            for (int g = 0; g < 4; ++g)
#pragma unroll
                for (int e = 0; e < 3; ++e)
                    ins4(entV[row][j][g][e], entC[row][j][g][e],
                         q1, e1, q2, e2, q3, e3, q4, e4);
#pragma unroll
            for (int m = 1; m <= 2; m <<= 1) {
                const float o1 = __shfl_xor(q1, m, 64); const int p1 = __shfl_xor(e1, m, 64);
                const float o2 = __shfl_xor(q2, m, 64); const int p2 = __shfl_xor(e2, m, 64);
                const float o3 = __shfl_xor(q3, m, 64); const int p3 = __shfl_xor(e3, m, 64);
                const float o4 = __shfl_xor(q4, m, 64); const int p4 = __shfl_xor(e4, m, 64);
                ins4(o1, p1, q1, e1, q2, e2, q3, e3, q4, e4);
                ins4(o2, p2, q1, e1, q2, e2, q3, e3, q4, e4);
                ins4(o3, p3, q1, e1, q2, e2, q3, e3, q4, e4);
                ins4(o4, p4, q1, e1, q2, e2, q3, e3, q4, e4);
            }
            const int cand = (j == 0) ? e1 : (j == 1) ? e2 : (j == 2) ? e3 : e4;

            // exact np f32 chain: ascending k, single accumulator (round-2 semantics)
            float e = 0.f;
            const float4* cbr = (const float4*)(cb + (size_t)cand * KDIM);
            const float4* rr  = (const float4*)(&resid[row][0]);
#pragma unroll 4
            for (int kk = 0; kk < 64; ++kk) {
                const float4 cv = cbr[kk];
                const float4 rv = rr[kk];
                e = fmaf(rv.x, cv.x, e); e = fmaf(rv.y, cv.y, e);
                e = fmaf(rv.z, cv.z, e); e = fmaf(rv.w, cv.w, e);
            }
            float be = e; int bc = cand;
#pragma unroll
            for (int m = 1; m <= 2; m <<= 1) {
                const float oe = __shfl_xor(be, m, 64);
                const int   oc = __shfl_xor(bc, m, 64);
                if (oe > be || (oe == be && oc < bc)) { be = oe; bc = oc; }
            }
            if (j == 0) { u_all[d][row] = be; c_all[d][row] = bc; }
        }
        __syncthreads();

        // ---- Phase C: resid = fl(resid - fl(cb[cw]*u))  (bitwise np) ----
        {
            const int row = tid >> 3, t8 = tid & 7;
            const float uu = u_all[d][row];
            const float* cr = cb + (size_t)c_all[d][row] * KDIM;
#pragma unroll
            for (int jj = 0; jj < 8; ++jj) {
                const int k = t8 * 4 + jj * 32;
                const float4 cv = *(const float4*)(cr + k);
                resid[row][k + 0] = __fsub_rn(resid[row][k + 0], __fmul_rn(cv.x, uu));
                resid[row][k + 1] = __fsub_rn(resid[row][k + 1], __fmul_rn(cv.y, uu));
                resid[row][k + 2] = __fsub_rn(resid[row][k + 2], __fmul_rn(cv.z, uu));
                resid[row][k + 3] = __fsub_rn(resid[row][k + 3], __fmul_rn(cv.w, uu));
            }
        }
        __syncthreads();
    }

    // ---- out = ((comp1+comp2)+comp3)+comp4, np's exact elementwise order ----
    {
        const int r = tid & 31, ks = tid >> 5;
        float* op = out + ((size_t)b * KDIM + ks * 32) * HWSZ + hw0 + r;
#pragma unroll
        for (int jj = 0; jj < 8; ++jj) {
            float ax = 0.f, ay = 0.f, az = 0.f, aw = 0.f;
            for (int d = 0; d < depth; ++d) {
                const float uu = u_all[d][r];
                const float* cr = cb + (size_t)c_all[d][r] * KDIM + ks * 32 + jj * 4;
                const float4 cv = *(const float4*)cr;
                ax = __fadd_rn(ax, __fmul_rn(cv.x, uu));
                ay = __fadd_rn(ay, __fmul_rn(cv.y, uu));
                az = __fadd_rn(az, __fmul_rn(cv.z, uu));
                aw = __fadd_rn(aw, __fmul_rn(cv.w, uu));
            }
            op[(size_t)(jj * 4 + 0) * HWSZ] = ax;
            op[(size_t)(jj * 4 + 1) * HWSZ] = ay;
            op[(size_t)(jj * 4 + 2) * HWSZ] = az;
            op[(size_t)(jj * 4 + 3) * HWSZ] = aw;
        }
    }
}

extern "C" void kernel_launch(void* const* d_in, const int* in_sizes, int n_in,
                              void* d_out, int out_size, void* d_ws, size_t ws_size,
                              hipStream_t stream)
{
    const float* x     = (const float*)d_in[0];
    const float* cb    = (const float*)d_in[1];
    const int*   depth = (const int*)d_in[2];
    float*       out   = (float*)d_out;
    bf16x8*      cbf   = (bf16x8*)d_ws;   // 512 KB fragment-packed bf16 codebook

    hipLaunchKernelGGL(make_cb_frag, dim3(128), dim3(256), 0, stream, cb, cbf);

    const int N      = in_sizes[0] / KDIM;  // 100352 pixel rows
    const int nblock = N / TM;              // 3136
    hipLaunchKernelGGL(vq_kernel, dim3(nblock), dim3(256), 0, stream,
                       x, cb, cbf, depth, out);
}